// Round 1
// baseline (129.140 us; speedup 1.0000x reference)
//
#include <hip/hip_runtime.h>
#include <math.h>

// Problem constants (fixed by setup_inputs): N_ref=128, N_src=128, D=256.
#define NREF 128
#define NSRC 128
#define DIM  256
#define EPS  1e-5f

// ---------------------------------------------------------------------------
// K1: one block per output element of the concatenated 256-vectors.
//   b in [0,128)   -> "row" block, owns ref index i=b       (scans over j)
//   b in [128,256) -> "col" block, owns src index j=b-128   (scans over i)
// Each block:
//   - redundantly computes normalized points (bitwise identical per block)
//   - computes its feat row/col (128 dots, same lane layout + reduction-tree
//     pairings as the previous feat_kernel -> bitwise-identical values;
//     f(i,j) from a row block == f(i,j) from a col block bitwise, since the
//     per-lane products commute and the tree is identical)
//   - argmax scans (ascending chunks, strict > == first occurrence) + gathers
// Writes 4 floats to ws: min_dist / feat_score / match_feat / match_dist.
// feat_mat is never materialized in global memory.
// ---------------------------------------------------------------------------
__global__ __launch_bounds__(512) void side_kernel(
    const float* __restrict__ points_c,
    const float* __restrict__ trans,
    const float* __restrict__ ref_feats,
    const float* __restrict__ src_feats,
    float* __restrict__ arrs)   // [0,256)=min_dist [256,512)=feat_score
                                // [512,768)=match_feat [768,1024)=match_dist
{
    __shared__ float px[256], py[256], pz[256], nsq[256];
    __shared__ float wred[12];
    __shared__ float red[4];
    __shared__ float featLds[128];
    __shared__ float cvD[8]; __shared__ int ciD[8];
    __shared__ float cvF[8]; __shared__ int ciF[8];

    const int b = blockIdx.x;
    const int t = threadIdx.x;
    const int w = t >> 6, l = t & 63;

    const bool isRow = (b < NREF);
    const int  me    = isRow ? b : (b - NREF);

    // ---- load my point (issue loads early; reductions come after feat loop)
    float x = 0.f, y = 0.f, z = 0.f;
    if (t < 256) {
        x = points_c[3 * t + 0];
        y = points_c[3 * t + 1];
        z = points_c[3 * t + 2];
        if (t >= NREF) {
            float nx = trans[0] * x + trans[1] * y + trans[2]  * z + trans[3];
            float ny = trans[4] * x + trans[5] * y + trans[6]  * z + trans[7];
            float nz = trans[8] * x + trans[9] * y + trans[10] * z + trans[11];
            x = nx; y = ny; z = nz;
        }
    }

    // ---- feat dots: 8 waves x 16 scanned indices, 2-dot ILP ----
    // Lane l holds float4 l of both operands; butterfly tree gives every lane
    // the full dot (lane-0 pairing identical to the old shfl_down tree).
    const float* __restrict__ myrow = (isRow ? ref_feats : src_feats) + me * DIM;
    const float4* __restrict__ other = (const float4*)(isRow ? src_feats : ref_feats);
    const float4 r = ((const float4*)myrow)[l];

    float bfv = -2.f; int bfi = 0;
    for (int m = 0; m < 16; m += 2) {
        const int j0 = w * 16 + m, j1 = j0 + 1;
        const float4 a0 = other[j0 * 64 + l];
        const float4 a1 = other[j1 * 64 + l];
        float acc0 = a0.x * r.x + a0.y * r.y + a0.z * r.z + a0.w * r.w;
        float acc1 = a1.x * r.x + a1.y * r.y + a1.z * r.z + a1.w * r.w;
        for (int off = 32; off >= 1; off >>= 1) {
            acc0 += __shfl_xor(acc0, off);
            acc1 += __shfl_xor(acc1, off);
        }
        if (l == 0) { featLds[j0] = acc0; featLds[j1] = acc1; }
        // sequential update keeps first-occurrence tie-break (j0 before j1)
        if (acc0 > bfv) { bfv = acc0; bfi = j0; }
        if (acc1 > bfv) { bfv = acc1; bfi = j1; }
    }
    if (l == 0) { cvF[w] = bfv; ciF[w] = bfi; }

    // ---- point normalization (same reduction trees as before) ----
    if (t < 256) {
        float sx = x, sy = y, sz = z;
        for (int off = 32; off >= 1; off >>= 1) {
            sx += __shfl_down(sx, off);
            sy += __shfl_down(sy, off);
            sz += __shfl_down(sz, off);
        }
        if (l == 0) { wred[w] = sx; wred[4 + w] = sy; wred[8 + w] = sz; }
    }
    __syncthreads();
    if (t == 0) {
        red[0] = (wred[0] + wred[1] + wred[2] + wred[3]) * (1.0f / 256.0f);
        red[1] = (wred[4] + wred[5] + wred[6] + wred[7]) * (1.0f / 256.0f);
        red[2] = (wred[8] + wred[9] + wred[10] + wred[11]) * (1.0f / 256.0f);
    }
    __syncthreads();
    if (t < 256) {
        x -= red[0]; y -= red[1]; z -= red[2];
        float n = x * x + y * y + z * z;
        float mx = n;
        for (int off = 32; off >= 1; off >>= 1)
            mx = fmaxf(mx, __shfl_down(mx, off));
        if (l == 0) wred[w] = mx;
    }
    __syncthreads();
    if (t == 0)
        red[3] = 1.0f / sqrtf(fmaxf(fmaxf(wred[0], wred[1]), fmaxf(wred[2], wred[3])));
    __syncthreads();
    if (t < 256) {
        const float inv = red[3];
        x *= inv; y *= inv; z *= inv;
        px[t] = x; py[t] = y; pz[t] = z;
        nsq[t] = x * x + y * y + z * z;
    }
    __syncthreads();

    // ---- dist argmax scan: 8 waves x 16, all lanes redundant (identical).
    // ONE shared d expression text for row and col roles -> bitwise match.
    float bdv = -1.f; int bdi = 0;
    for (int m = 0; m < 16; ++m) {
        const int jj = w * 16 + m;
        const int i = isRow ? me : jj;
        const int j = isRow ? jj : me;
        float d = nsq[i] + nsq[128 + j]
                - 2.0f * (px[i] * px[128 + j] + py[i] * py[128 + j] + pz[i] * pz[128 + j]);
        d = fmaxf(d, 0.f);
        const float v = expf(-d);
        if (v > bdv) { bdv = v; bdi = jj; }
    }
    if (l == 0) { cvD[w] = bdv; ciD[w] = bdi; }
    __syncthreads();

    // ---- combine chunks (ascending wave order, strict >) + gathers ----
    if (t == 0) {
        float bv = -1.f; int bi = 0;
        for (int q = 0; q < 8; ++q)
            if (cvD[q] > bv) { bv = cvD[q]; bi = ciD[q]; }
        float fv = -2.f; int fi = 0;
        for (int q = 0; q < 8; ++q)
            if (cvF[q] > fv) { fv = cvF[q]; fi = ciF[q]; }
        const float fscore = featLds[bi];       // feat at dist-argmax
        const int i = isRow ? me : fi;          // dist at feat-argmax
        const int j = isRow ? fi : me;
        float d = nsq[i] + nsq[128 + j]
                - 2.0f * (px[i] * px[128 + j] + py[i] * py[128 + j] + pz[i] * pz[128 + j]);
        d = fmaxf(d, 0.f);
        const float mdist = expf(-d);
        const int gi = isRow ? me : NREF + me;
        arrs[gi]       = bv;        // min_dist
        arrs[256 + gi] = fscore;    // feat_score
        arrs[512 + gi] = fv;        // match_feat
        arrs[768 + gi] = mdist;     // match_dist
    }
}

// ---------------------------------------------------------------------------
// K2: single block x 512 threads: stable ranks -> geo (LDS only) -> y1
// (per-channel wave dots, bitwise-identical tree to old mlp1) -> GN1 ->
// y2 (old mlp2 tree) -> GN2 -> final. Replaces 4 kernels with one.
// ---------------------------------------------------------------------------
__global__ __launch_bounds__(512) void tail_kernel(
    const float* __restrict__ arrs,
    const float* __restrict__ W1, const float* __restrict__ b1,
    const float* __restrict__ g1, const float* __restrict__ bt1,
    const float* __restrict__ W2, const float* __restrict__ b2,
    const float* __restrict__ g2, const float* __restrict__ bt2,
    const float* __restrict__ W3, const float* __restrict__ b3,
    float* __restrict__ out)
{
    __shared__ __align__(16) float arrD[256], arrFS[256], arrMF[256], arrMD[256];
    __shared__ __align__(16) float geoLds[512];
    __shared__ __align__(16) float h1s[256];
    __shared__ float y1s[256];
    __shared__ float stats[16];
    __shared__ float y2s[128], h2s[128];

    const int t = threadIdx.x;
    const int w = t >> 6, l = t & 63;

    if (t < 256) {
        arrD[t]  = arrs[t];
        arrFS[t] = arrs[256 + t];
        arrMF[t] = arrs[512 + t];
        arrMD[t] = arrs[768 + t];
    }
    __syncthreads();

    // ---- stable descending ranks (== jnp.argsort(-v) scatter) ----
    // t<256: rank in min_dist; t>=256: rank in match_feat. Integer counts ->
    // bitwise-identical to the old chunked P5.
    {
        const int e = t & 255;
        const float* __restrict__ A = (t < 256) ? arrD : arrMF;
        const float v = A[e];
        int rk = 0;
        for (int jb = 0; jb < 256; jb += 4) {
            const float4 u = ((const float4*)A)[jb >> 2];
            rk += (u.x > v) || (u.x == v && (jb + 0) < e);
            rk += (u.y > v) || (u.y == v && (jb + 1) < e);
            rk += (u.z > v) || (u.z == v && (jb + 2) < e);
            rk += (u.w > v) || (u.w == v && (jb + 3) < e);
        }
        if (t < 256) geoLds[rk]       = arrD[e] * arrFS[e];
        else         geoLds[256 + rk] = arrMD[e] * arrMF[e];
    }
    __syncthreads();

    // ---- y1: 8 waves x 32 channels; exact old-mlp1 lane layout + tree ----
    {
        const float4 ga = ((const float4*)geoLds)[l];
        const float4 gb = ((const float4*)geoLds)[64 + l];
        for (int m = 0; m < 32; ++m) {
            const int c = (w << 5) + m;
            const float4* __restrict__ wrow = (const float4*)(W1 + c * 512);
            const float4 a = wrow[l];
            const float4 bq = wrow[64 + l];
            float acc = a.x * ga.x + a.y * ga.y + a.z * ga.z + a.w * ga.w
                      + bq.x * gb.x + bq.y * gb.y + bq.z * gb.z + bq.w * gb.w;
            acc += __shfl_down(acc, 32);
            acc += __shfl_down(acc, 16);
            acc += __shfl_down(acc, 8);
            acc += __shfl_down(acc, 4);
            acc += __shfl_down(acc, 2);
            acc += __shfl_down(acc, 1);
            if (l == 0) y1s[c] = acc + b1[c];
        }
    }
    __syncthreads();

    // ---- GN1 (groups of 32) + relu ----
    if (t < 8) {
        float s = 0.f;
        for (int k = 0; k < 32; ++k) s += y1s[(t << 5) + k];
        const float mean = s * (1.0f / 32.0f);
        float q = 0.f;
        for (int k = 0; k < 32; ++k) { const float d = y1s[(t << 5) + k] - mean; q += d * d; }
        stats[t] = mean;
        stats[8 + t] = rsqrtf(q * (1.0f / 32.0f) + EPS);
    }
    __syncthreads();
    if (t < 256) {
        const int g = t >> 5;
        const float xn = (y1s[t] - stats[g]) * stats[8 + g];
        h1s[t] = fmaxf(xn * g1[t] + bt1[t], 0.f);
    }
    __syncthreads();

    // ---- y2: 8 waves x 16 channels; exact old-mlp2 lane layout + tree ----
    {
        const float4 hv = ((const float4*)h1s)[l];
        for (int m = 0; m < 16; ++m) {
            const int c = (w << 4) + m;
            const float4 wv = ((const float4*)(W2 + c * 256))[l];
            float acc = wv.x * hv.x + wv.y * hv.y + wv.z * hv.z + wv.w * hv.w;
            acc += __shfl_down(acc, 32);
            acc += __shfl_down(acc, 16);
            acc += __shfl_down(acc, 8);
            acc += __shfl_down(acc, 4);
            acc += __shfl_down(acc, 2);
            acc += __shfl_down(acc, 1);
            if (l == 0) y2s[c] = acc + b2[c];
        }
    }
    __syncthreads();

    // ---- GN2 (groups of 16) + relu (exact old final_kernel math) ----
    if (t < 128) {
        const int g = t >> 4;
        float s = 0.f;
        for (int k = 0; k < 16; ++k) s += y2s[(g << 4) + k];
        const float mean = s * (1.0f / 16.0f);
        float q = 0.f;
        for (int k = 0; k < 16; ++k) { const float d = y2s[(g << 4) + k] - mean; q += d * d; }
        const float xn = (y2s[t] - mean) * rsqrtf(q * (1.0f / 16.0f) + EPS);
        h2s[t] = fmaxf(xn * g2[t] + bt2[t], 0.f);
    }
    __syncthreads();
    if (t < 128) {
        float acc = W3[w * 128 + l] * h2s[l]
                  + W3[w * 128 + 64 + l] * h2s[64 + l];
        acc += __shfl_down(acc, 32);
        acc += __shfl_down(acc, 16);
        acc += __shfl_down(acc, 8);
        acc += __shfl_down(acc, 4);
        acc += __shfl_down(acc, 2);
        acc += __shfl_down(acc, 1);
        if (l == 0) out[w] = acc + b3[w];
    }
}

// ---------------------------------------------------------------------------
extern "C" void kernel_launch(void* const* d_in, const int* in_sizes, int n_in,
                              void* d_out, int out_size, void* d_ws, size_t ws_size,
                              hipStream_t stream)
{
    const float* points_c  = (const float*)d_in[0];
    const float* ref_feats = (const float*)d_in[1];
    const float* src_feats = (const float*)d_in[2];
    const float* trans     = (const float*)d_in[3];
    const float* W1  = (const float*)d_in[4];
    const float* b1  = (const float*)d_in[5];
    const float* g1  = (const float*)d_in[6];
    const float* bt1 = (const float*)d_in[7];
    const float* W2  = (const float*)d_in[8];
    const float* b2  = (const float*)d_in[9];
    const float* g2  = (const float*)d_in[10];
    const float* bt2 = (const float*)d_in[11];
    const float* W3  = (const float*)d_in[12];
    const float* b3  = (const float*)d_in[13];
    // d_in[14] = ref_length (int, == 128): fixed at compile time.

    // ws: arrs occupies floats [0,1024) = 4 KB. No feat_mat, no geo/y1/y2
    // in global memory anymore (all LDS-resident in tail_kernel).
    float* arrs = (float*)d_ws;

    side_kernel<<<dim3(256), dim3(512), 0, stream>>>(points_c, trans, ref_feats, src_feats, arrs);
    tail_kernel<<<dim3(1), dim3(512), 0, stream>>>(arrs, W1, b1, g1, bt1,
                                                   W2, b2, g2, bt2, W3, b3,
                                                   (float*)d_out);
}

// Round 2
// 104.288 us; speedup vs baseline: 1.2383x; 1.2383x over previous
//
#include <hip/hip_runtime.h>
#include <math.h>

// Problem constants (fixed by setup_inputs): N_ref=128, N_src=128, D=256.
#define NREF 128
#define NSRC 128
#define DIM  256
#define EPS  1e-5f

// ---------------------------------------------------------------------------
// K1: one block per output element of the concatenated 256-vectors.
//   b in [0,128)   -> "row" block, owns ref index i=b       (scans over j)
//   b in [128,256) -> "col" block, owns src index j=b-128   (scans over i)
// Verified bitwise-exact in round 1 (absmax 0.0) — unchanged.
// Writes 4 floats to ws: min_dist / feat_score / match_feat / match_dist.
// ---------------------------------------------------------------------------
__global__ __launch_bounds__(512) void side_kernel(
    const float* __restrict__ points_c,
    const float* __restrict__ trans,
    const float* __restrict__ ref_feats,
    const float* __restrict__ src_feats,
    float* __restrict__ arrs)   // [0,256)=min_dist [256,512)=feat_score
                                // [512,768)=match_feat [768,1024)=match_dist
{
    __shared__ float px[256], py[256], pz[256], nsq[256];
    __shared__ float wred[12];
    __shared__ float red[4];
    __shared__ float featLds[128];
    __shared__ float cvD[8]; __shared__ int ciD[8];
    __shared__ float cvF[8]; __shared__ int ciF[8];

    const int b = blockIdx.x;
    const int t = threadIdx.x;
    const int w = t >> 6, l = t & 63;

    const bool isRow = (b < NREF);
    const int  me    = isRow ? b : (b - NREF);

    // ---- load my point (issue loads early; reductions come after feat loop)
    float x = 0.f, y = 0.f, z = 0.f;
    if (t < 256) {
        x = points_c[3 * t + 0];
        y = points_c[3 * t + 1];
        z = points_c[3 * t + 2];
        if (t >= NREF) {
            float nx = trans[0] * x + trans[1] * y + trans[2]  * z + trans[3];
            float ny = trans[4] * x + trans[5] * y + trans[6]  * z + trans[7];
            float nz = trans[8] * x + trans[9] * y + trans[10] * z + trans[11];
            x = nx; y = ny; z = nz;
        }
    }

    // ---- feat dots: 8 waves x 16 scanned indices, 2-dot ILP ----
    const float* __restrict__ myrow = (isRow ? ref_feats : src_feats) + me * DIM;
    const float4* __restrict__ other = (const float4*)(isRow ? src_feats : ref_feats);
    const float4 r = ((const float4*)myrow)[l];

    float bfv = -2.f; int bfi = 0;
    for (int m = 0; m < 16; m += 2) {
        const int j0 = w * 16 + m, j1 = j0 + 1;
        const float4 a0 = other[j0 * 64 + l];
        const float4 a1 = other[j1 * 64 + l];
        float acc0 = a0.x * r.x + a0.y * r.y + a0.z * r.z + a0.w * r.w;
        float acc1 = a1.x * r.x + a1.y * r.y + a1.z * r.z + a1.w * r.w;
        for (int off = 32; off >= 1; off >>= 1) {
            acc0 += __shfl_xor(acc0, off);
            acc1 += __shfl_xor(acc1, off);
        }
        if (l == 0) { featLds[j0] = acc0; featLds[j1] = acc1; }
        if (acc0 > bfv) { bfv = acc0; bfi = j0; }
        if (acc1 > bfv) { bfv = acc1; bfi = j1; }
    }
    if (l == 0) { cvF[w] = bfv; ciF[w] = bfi; }

    // ---- point normalization (same reduction trees as round 0) ----
    if (t < 256) {
        float sx = x, sy = y, sz = z;
        for (int off = 32; off >= 1; off >>= 1) {
            sx += __shfl_down(sx, off);
            sy += __shfl_down(sy, off);
            sz += __shfl_down(sz, off);
        }
        if (l == 0) { wred[w] = sx; wred[4 + w] = sy; wred[8 + w] = sz; }
    }
    __syncthreads();
    if (t == 0) {
        red[0] = (wred[0] + wred[1] + wred[2] + wred[3]) * (1.0f / 256.0f);
        red[1] = (wred[4] + wred[5] + wred[6] + wred[7]) * (1.0f / 256.0f);
        red[2] = (wred[8] + wred[9] + wred[10] + wred[11]) * (1.0f / 256.0f);
    }
    __syncthreads();
    if (t < 256) {
        x -= red[0]; y -= red[1]; z -= red[2];
        float n = x * x + y * y + z * z;
        float mx = n;
        for (int off = 32; off >= 1; off >>= 1)
            mx = fmaxf(mx, __shfl_down(mx, off));
        if (l == 0) wred[w] = mx;
    }
    __syncthreads();
    if (t == 0)
        red[3] = 1.0f / sqrtf(fmaxf(fmaxf(wred[0], wred[1]), fmaxf(wred[2], wred[3])));
    __syncthreads();
    if (t < 256) {
        const float inv = red[3];
        x *= inv; y *= inv; z *= inv;
        px[t] = x; py[t] = y; pz[t] = z;
        nsq[t] = x * x + y * y + z * z;
    }
    __syncthreads();

    // ---- dist argmax scan: 8 waves x 16, all lanes redundant (identical) ----
    float bdv = -1.f; int bdi = 0;
    for (int m = 0; m < 16; ++m) {
        const int jj = w * 16 + m;
        const int i = isRow ? me : jj;
        const int j = isRow ? jj : me;
        float d = nsq[i] + nsq[128 + j]
                - 2.0f * (px[i] * px[128 + j] + py[i] * py[128 + j] + pz[i] * pz[128 + j]);
        d = fmaxf(d, 0.f);
        const float v = expf(-d);
        if (v > bdv) { bdv = v; bdi = jj; }
    }
    if (l == 0) { cvD[w] = bdv; ciD[w] = bdi; }
    __syncthreads();

    // ---- combine chunks (ascending wave order, strict >) + gathers ----
    if (t == 0) {
        float bv = -1.f; int bi = 0;
        for (int q = 0; q < 8; ++q)
            if (cvD[q] > bv) { bv = cvD[q]; bi = ciD[q]; }
        float fv = -2.f; int fi = 0;
        for (int q = 0; q < 8; ++q)
            if (cvF[q] > fv) { fv = cvF[q]; fi = ciF[q]; }
        const float fscore = featLds[bi];       // feat at dist-argmax
        const int i = isRow ? me : fi;          // dist at feat-argmax
        const int j = isRow ? fi : me;
        float d = nsq[i] + nsq[128 + j]
                - 2.0f * (px[i] * px[128 + j] + py[i] * py[128 + j] + pz[i] * pz[128 + j]);
        d = fmaxf(d, 0.f);
        const float mdist = expf(-d);
        const int gi = isRow ? me : NREF + me;
        arrs[gi]       = bv;        // min_dist
        arrs[256 + gi] = fscore;    // feat_score
        arrs[512 + gi] = fv;        // match_feat
        arrs[768 + gi] = mdist;     // match_dist
    }
}

// ---------------------------------------------------------------------------
// K2: y1[c] for c = blockIdx.x. 256 blocks x 256 threads.
// Each block redundantly recomputes the stable descending ranks from arrs
// (integer compares on identical values -> identical ranks in every block),
// scatters geo into LDS, then wave 0 computes the channel dot with the EXACT
// round-0 mlp1 float4 + shfl_down tree (bitwise-identical y1).
// W1's 512 KB streams chip-wide in parallel (one row per block).
// ---------------------------------------------------------------------------
__global__ __launch_bounds__(256) void mlp1_kernel(
    const float* __restrict__ arrs,
    const float* __restrict__ W1, const float* __restrict__ b1,
    float* __restrict__ y1)
{
    __shared__ __align__(16) float arrD[256], arrFS[256], arrMF[256], arrMD[256];
    __shared__ __align__(16) float geoLds[512];
    const int c = blockIdx.x;
    const int t = threadIdx.x;

    arrD[t]  = arrs[t];
    arrFS[t] = arrs[256 + t];
    arrMF[t] = arrs[512 + t];
    arrMD[t] = arrs[768 + t];
    __syncthreads();

    // ---- stable descending ranks (== jnp.argsort(-v) scatter), 1 elem each
    {
        const float vD = arrD[t];
        const float vF = arrMF[t];
        int rD = 0, rF = 0;
        for (int jb = 0; jb < 64; ++jb) {
            const float4 uD = ((const float4*)arrD)[jb];
            const float4 uF = ((const float4*)arrMF)[jb];
            const int j0 = 4 * jb;
            rD += (uD.x > vD) || (uD.x == vD && (j0 + 0) < t);
            rD += (uD.y > vD) || (uD.y == vD && (j0 + 1) < t);
            rD += (uD.z > vD) || (uD.z == vD && (j0 + 2) < t);
            rD += (uD.w > vD) || (uD.w == vD && (j0 + 3) < t);
            rF += (uF.x > vF) || (uF.x == vF && (j0 + 0) < t);
            rF += (uF.y > vF) || (uF.y == vF && (j0 + 1) < t);
            rF += (uF.z > vF) || (uF.z == vF && (j0 + 2) < t);
            rF += (uF.w > vF) || (uF.w == vF && (j0 + 3) < t);
        }
        geoLds[rD]       = vD * arrFS[t];
        geoLds[256 + rF] = arrMD[t] * vF;
    }
    __syncthreads();

    // ---- exact round-0 mlp1 dot (wave 0 only) ----
    if (t < 64) {
        const int l = t;
        const float4 ga = ((const float4*)geoLds)[l];
        const float4 gb = ((const float4*)geoLds)[64 + l];
        const float4* __restrict__ wrow = (const float4*)(W1 + c * 512);
        const float4 a = wrow[l];
        const float4 b = wrow[64 + l];
        float acc = a.x * ga.x + a.y * ga.y + a.z * ga.z + a.w * ga.w
                  + b.x * gb.x + b.y * gb.y + b.z * gb.z + b.w * gb.w;
        acc += __shfl_down(acc, 32);
        acc += __shfl_down(acc, 16);
        acc += __shfl_down(acc, 8);
        acc += __shfl_down(acc, 4);
        acc += __shfl_down(acc, 2);
        acc += __shfl_down(acc, 1);
        if (l == 0) y1[c] = acc + b1[c];
    }
}

// ---------------------------------------------------------------------------
// K3: h1 = relu(GN8(y1)*g1+bt1); y2[c] = h1 . W2[c,:] + b2[c].
// 128 blocks x 64 threads — round-0 kernel verbatim (bitwise-verified).
// ---------------------------------------------------------------------------
__global__ __launch_bounds__(64) void mlp2_kernel(
    const float* __restrict__ y1,
    const float* __restrict__ g1, const float* __restrict__ bt1,
    const float* __restrict__ W2, const float* __restrict__ b2,
    float* __restrict__ y2)
{
    __shared__ __align__(16) float y1s[256];
    __shared__ float stats[16];   // mean[8], invstd[8]
    const int c = blockIdx.x, l = threadIdx.x;
    ((float4*)y1s)[l] = ((const float4*)y1)[l];
    __syncthreads();
    if (l < 8) {
        float s = 0.f;
        for (int k = 0; k < 32; ++k) s += y1s[(l << 5) + k];
        const float mean = s * (1.0f / 32.0f);
        float q = 0.f;
        for (int k = 0; k < 32; ++k) { const float d = y1s[(l << 5) + k] - mean; q += d * d; }
        const float var = q * (1.0f / 32.0f);
        stats[l] = mean;
        stats[8 + l] = rsqrtf(var + EPS);
    }
    __syncthreads();
    const float4 gg = ((const float4*)g1)[l];
    const float4 bb = ((const float4*)bt1)[l];
    const int g = l >> 3;
    const float mean = stats[g], inv = stats[8 + g];
    const float4 yv = ((const float4*)y1s)[l];
    float4 h;
    h.x = fmaxf((yv.x - mean) * inv * gg.x + bb.x, 0.f);
    h.y = fmaxf((yv.y - mean) * inv * gg.y + bb.y, 0.f);
    h.z = fmaxf((yv.z - mean) * inv * gg.z + bb.z, 0.f);
    h.w = fmaxf((yv.w - mean) * inv * gg.w + bb.w, 0.f);
    const float4 wv = ((const float4*)(W2 + c * 256))[l];
    float acc = wv.x * h.x + wv.y * h.y + wv.z * h.z + wv.w * h.w;
    acc += __shfl_down(acc, 32);
    acc += __shfl_down(acc, 16);
    acc += __shfl_down(acc, 8);
    acc += __shfl_down(acc, 4);
    acc += __shfl_down(acc, 2);
    acc += __shfl_down(acc, 1);
    if (l == 0) y2[c] = acc + b2[c];
}

// ---------------------------------------------------------------------------
// K4: h2 = relu(GN8(y2)*g2+bt2); out = h2 @ W3.T + b3. 1 block x 128.
// Round-0 kernel verbatim (bitwise-verified).
// ---------------------------------------------------------------------------
__global__ __launch_bounds__(128) void final_kernel(
    const float* __restrict__ y2,
    const float* __restrict__ g2, const float* __restrict__ bt2,
    const float* __restrict__ W3, const float* __restrict__ b3,
    float* __restrict__ out)
{
    __shared__ float y2s[128], h2[128];
    const int t = threadIdx.x;
    y2s[t] = y2[t];
    __syncthreads();
    {
        const int g = t >> 4;
        float s = 0.f;
        for (int k = 0; k < 16; ++k) s += y2s[(g << 4) + k];
        const float mean = s * (1.0f / 16.0f);
        float q = 0.f;
        for (int k = 0; k < 16; ++k) { const float d = y2s[(g << 4) + k] - mean; q += d * d; }
        const float var = q * (1.0f / 16.0f);
        const float xn = (y2s[t] - mean) * rsqrtf(var + EPS);
        h2[t] = fmaxf(xn * g2[t] + bt2[t], 0.f);
    }
    __syncthreads();
    const int wave = t >> 6, lane = t & 63;
    float acc = W3[wave * 128 + lane] * h2[lane]
              + W3[wave * 128 + 64 + lane] * h2[64 + lane];
    acc += __shfl_down(acc, 32);
    acc += __shfl_down(acc, 16);
    acc += __shfl_down(acc, 8);
    acc += __shfl_down(acc, 4);
    acc += __shfl_down(acc, 2);
    acc += __shfl_down(acc, 1);
    if (lane == 0) out[wave] = acc + b3[wave];
}

// ---------------------------------------------------------------------------
extern "C" void kernel_launch(void* const* d_in, const int* in_sizes, int n_in,
                              void* d_out, int out_size, void* d_ws, size_t ws_size,
                              hipStream_t stream)
{
    const float* points_c  = (const float*)d_in[0];
    const float* ref_feats = (const float*)d_in[1];
    const float* src_feats = (const float*)d_in[2];
    const float* trans     = (const float*)d_in[3];
    const float* W1  = (const float*)d_in[4];
    const float* b1  = (const float*)d_in[5];
    const float* g1  = (const float*)d_in[6];
    const float* bt1 = (const float*)d_in[7];
    const float* W2  = (const float*)d_in[8];
    const float* b2  = (const float*)d_in[9];
    const float* g2  = (const float*)d_in[10];
    const float* bt2 = (const float*)d_in[11];
    const float* W3  = (const float*)d_in[12];
    const float* b3  = (const float*)d_in[13];
    // d_in[14] = ref_length (int, == 128): fixed at compile time.

    // ws layout (floats): arrs [0,1024), y1 [1024,1280), y2 [1280,1408).
    float* arrs = (float*)d_ws;
    float* y1   = arrs + 1024;
    float* y2   = arrs + 1280;

    side_kernel<<<dim3(256), dim3(512), 0, stream>>>(points_c, trans, ref_feats, src_feats, arrs);
    mlp1_kernel<<<dim3(256), dim3(256), 0, stream>>>(arrs, W1, b1, y1);
    mlp2_kernel<<<dim3(128), dim3(64), 0, stream>>>(y1, g1, bt1, W2, b2, y2);
    final_kernel<<<dim3(1), dim3(128), 0, stream>>>(y2, g2, bt2, W3, b3, (float*)d_out);
}